// Round 2
// baseline (800.412 us; speedup 1.0000x reference)
//
#include <hip/hip_runtime.h>
#include <hip/hip_bf16.h>
#include <math.h>

// ---------------- problem constants ----------------
#define HID    2048
#define NH     16
#define D_NOPE 128
#define D_ROPE 64
#define HD     192      // HEAD_DIM
#define V_DIM  128
#define KV_RANK 512
#define Q_RANK  1536
#define BATCH  2
#define SEQ    2048
#define ROWS   (BATCH*SEQ)   // 4096

typedef __attribute__((ext_vector_type(8))) short short8;
typedef __attribute__((ext_vector_type(4))) float f32x4;

__device__ __forceinline__ unsigned short f2bf(float x) {
    unsigned int u = __float_as_uint(x);
    unsigned int r = (u + 0x7fffu + ((u >> 16) & 1u)) >> 16;
    return (unsigned short)r;
}
__device__ __forceinline__ float bf2f(unsigned short u) {
    return __uint_as_float((unsigned int)u << 16);
}

typedef const __attribute__((address_space(1))) unsigned int gu32;
typedef __attribute__((address_space(3))) unsigned int lu32;
__device__ __forceinline__ void gl_lds16(const void* g, void* l) {
    __builtin_amdgcn_global_load_lds((gu32*)g, (lu32*)l, 16, 0, 0);
}

// ---------------- RoPE cos/sin table ----------------
__global__ void rope_table_kernel(float* __restrict__ table) {
    int idx = blockIdx.x * 256 + threadIdx.x;   // < 2048*64
    int pos = idx >> 6, u = idx & 63;
    int i = u & 31;
    float invf = expf((float)i * (-9.210340371976184f / 32.0f));
    float ang = (float)pos * invf;
    table[idx] = (u < 32) ? cosf(ang) : sinf(ang);
}

// ---------------- fp32 -> bf16 elementwise ----------------
__global__ __launch_bounds__(256) void convert_bf16_kernel(
    const float* __restrict__ src, unsigned short* __restrict__ dst)
{
    size_t i = (size_t)(blockIdx.x * 256 + threadIdx.x) * 4;
    float4 v = *(const float4*)(src + i);
    ushort4 u;
    u.x = f2bf(v.x); u.y = f2bf(v.y); u.z = f2bf(v.z); u.w = f2bf(v.w);
    *(ushort4*)(dst + i) = u;
}

// ---------------- fp32 (K x N) -> bf16 transposed (N x K) ----------------
__global__ __launch_bounds__(256) void transpose_bf16_kernel(
    const float* __restrict__ src, unsigned short* __restrict__ dst, int K, int N)
{
    __shared__ float T[64][65];
    const int n0 = blockIdx.x * 64, k0 = blockIdx.y * 64;
    const int t = threadIdx.x;
    const int c4 = t & 15, r = t >> 4;
    #pragma unroll
    for (int i = 0; i < 4; i++) {
        int row = r + i * 16;
        float4 v = *(const float4*)(src + (size_t)(k0 + row) * N + n0 + c4 * 4);
        T[row][c4*4+0] = v.x; T[row][c4*4+1] = v.y;
        T[row][c4*4+2] = v.z; T[row][c4*4+3] = v.w;
    }
    __syncthreads();
    #pragma unroll
    for (int i = 0; i < 4; i++) {
        int nrow = r + i * 16;
        ushort4 u;
        u.x = f2bf(T[c4*4+0][nrow]); u.y = f2bf(T[c4*4+1][nrow]);
        u.z = f2bf(T[c4*4+2][nrow]); u.w = f2bf(T[c4*4+3][nrow]);
        *(ushort4*)(dst + (size_t)(n0 + nrow) * K + k0 + c4 * 4) = u;
    }
}

// ---------------- bf16 MFMA GEMM: C(M,N) = A(M,K) @ Bt(N,K)^T ----------------
template<int BN, bool OUT_BF16>
__global__ __launch_bounds__(256) void bgemm_kernel(
    const unsigned short* __restrict__ A,    // M x K bf16
    const unsigned short* __restrict__ Bt,   // N x K bf16
    void* __restrict__ Cv,                   // M x N (fp32 or bf16)
    int M, int N, int K)
{
    constexpr int NT = BN / 32;
    constexpr int NSLAB = 8 + BN / 16;
    const int tid  = threadIdx.x;
    const int w    = tid >> 6;
    const int lane = tid & 63;
    const int n16  = lane & 15, quad = lane >> 4;
    const int m0 = blockIdx.y * 128;
    const int n0 = blockIdx.x * BN;
    const int moff = (w & 1) * 64;
    const int noff = (w >> 1) * (NT * 16);

    __shared__ unsigned short As[128 * 32];
    __shared__ unsigned short Bs[BN * 32];

    const unsigned short* gp[4];
    unsigned short* lp[4];
    int ns = 0;
    const int rl = lane >> 2, sc = lane & 3;
    for (int s = w; s < NSLAB; s += 4) {
        int kc = sc ^ (((s * 16 + rl) >> 1) & 3);   // XOR swizzle
        if (s < 8) {
            gp[ns] = A + (size_t)(m0 + s * 16 + rl) * K + kc * 8;
            lp[ns] = As + s * 512;
        } else {
            int sb = s - 8;
            gp[ns] = Bt + (size_t)(n0 + sb * 16 + rl) * K + kc * 8;
            lp[ns] = Bs + sb * 512;
        }
        ns++;
    }

    const int swz = (quad ^ ((n16 >> 1) & 3)) * 8;
    int aoff[4], boff[NT];
    #pragma unroll
    for (int mt = 0; mt < 4; mt++) aoff[mt] = (moff + mt * 16 + n16) * 32 + swz;
    #pragma unroll
    for (int nt = 0; nt < NT; nt++) boff[nt] = (noff + nt * 16 + n16) * 32 + swz;

    f32x4 acc[4][NT];
    #pragma unroll
    for (int mt = 0; mt < 4; mt++)
        #pragma unroll
        for (int nt = 0; nt < NT; nt++) acc[mt][nt] = (f32x4){0.f, 0.f, 0.f, 0.f};

    for (int k0 = 0; k0 < K; k0 += 32) {
        #pragma unroll
        for (int j = 0; j < 4; j++) if (j < ns) gl_lds16(gp[j], lp[j]);
        #pragma unroll
        for (int j = 0; j < 4; j++) if (j < ns) gp[j] += 32;
        __syncthreads();

        short8 af[4], bfr[NT];
        #pragma unroll
        for (int mt = 0; mt < 4; mt++) af[mt] = *(const short8*)(As + aoff[mt]);
        #pragma unroll
        for (int nt = 0; nt < NT; nt++) bfr[nt] = *(const short8*)(Bs + boff[nt]);
        #pragma unroll
        for (int mt = 0; mt < 4; mt++)
            #pragma unroll
            for (int nt = 0; nt < NT; nt++)
                acc[mt][nt] = __builtin_amdgcn_mfma_f32_16x16x32_bf16(
                    af[mt], bfr[nt], acc[mt][nt], 0, 0, 0);
        __syncthreads();
    }

    #pragma unroll
    for (int mt = 0; mt < 4; mt++)
        #pragma unroll
        for (int nt = 0; nt < NT; nt++)
            #pragma unroll
            for (int r = 0; r < 4; r++) {
                size_t idx = (size_t)(m0 + moff + mt * 16 + quad * 4 + r) * N
                           + n0 + noff + nt * 16 + n16;
                if (OUT_BF16) ((unsigned short*)Cv)[idx] = f2bf(acc[mt][nt][r]);
                else          ((float*)Cv)[idx] = acc[mt][nt][r];
            }
}

// ---------------- RMSNorm(kv_c)->bf16 + RoPE(k_rope)->bf16 ----------------
__global__ __launch_bounds__(256) void kv_norm_rope_kernel(
    const float* __restrict__ kv_full,    // (4096, 576)
    const float* __restrict__ w,          // (512,)
    const float* __restrict__ table,
    unsigned short* __restrict__ kv_cb,   // (4096, 512) bf16
    unsigned short* __restrict__ k_rope_b)// (4096, 64) bf16 roped
{
    const int row = blockIdx.x;
    const int tid = threadIdx.x;
    const float* src = kv_full + (size_t)row * 576;
    float v0 = src[tid], v1 = src[tid + 256];
    float ss = v0*v0 + v1*v1;
    #pragma unroll
    for (int off = 32; off > 0; off >>= 1) ss += __shfl_down(ss, off);
    __shared__ float red[4];
    __shared__ float msh;
    if ((tid & 63) == 0) red[tid >> 6] = ss;
    __syncthreads();
    if (tid == 0) msh = (red[0] + red[1] + red[2] + red[3]) * (1.0f / 512.0f);
    __syncthreads();
    float f = rsqrtf(msh + 1e-6f);
    kv_cb[(size_t)row * 512 + tid]       = f2bf(v0 * f * w[tid]);
    kv_cb[(size_t)row * 512 + tid + 256] = f2bf(v1 * f * w[tid + 256]);
    if (tid < 32) {
        int pos = row & (SEQ - 1);
        float c = table[pos*64 + tid], s = table[pos*64 + 32 + tid];
        float x1 = src[512 + tid], x2 = src[512 + 32 + tid];
        k_rope_b[(size_t)row * 64 + tid]      = f2bf(x1*c - x2*s);
        k_rope_b[(size_t)row * 64 + 32 + tid] = f2bf(x2*c + x1*s);
    }
}

// ---------------- RoPE on q, in place, bf16 ----------------
__global__ __launch_bounds__(256) void q_rope_b_kernel(
    unsigned short* __restrict__ qb16, const float* __restrict__ table)
{
    int g = blockIdx.x * 8 + (threadIdx.x >> 5);  // (row,h) pair id, < 65536
    int i = threadIdx.x & 31;
    int row = g >> 4, h = g & 15;
    size_t base = (size_t)row * (NH*HD) + h * HD + D_NOPE;
    int pos = row & (SEQ - 1);
    float c = table[pos*64 + i], s = table[pos*64 + 32 + i];
    float x1 = bf2f(qb16[base + i]), x2 = bf2f(qb16[base + 32 + i]);
    qb16[base + i]      = f2bf(x1*c - x2*s);
    qb16[base + 32 + i] = f2bf(x2*c + x1*s);
}

// ---------------- pack V transposed: kv_exp_b(v) -> Vmat bf16 [b][h][128][s] --
__global__ __launch_bounds__(256) void pack_vt_kernel(
    const unsigned short* __restrict__ kv_exp_b, unsigned short* __restrict__ Vmat)
{
    const int st = blockIdx.x;     // 32 tiles of 64 tokens
    const int h  = blockIdx.y;
    const int b  = blockIdx.z;
    const int tid = threadIdx.x;
    const int s0 = st * 64;
    __shared__ float T[64][129];

    #pragma unroll
    for (int t = 0; t < 8; t++) {
        int idx = tid + t * 256;            // 0..2047 ushort4 slots
        int tokr = idx >> 5, c4 = idx & 31;
        ushort4 u = *(const ushort4*)(kv_exp_b +
            ((size_t)(b*SEQ) + s0 + tokr) * 4096 + h*256 + 128 + c4*4);
        T[tokr][c4*4+0] = bf2f(u.x); T[tokr][c4*4+1] = bf2f(u.y);
        T[tokr][c4*4+2] = bf2f(u.z); T[tokr][c4*4+3] = bf2f(u.w);
    }
    __syncthreads();

    int d = tid >> 1, sh = (tid & 1) * 32;
    unsigned short* op = Vmat + ((size_t)((b*NH + h) * V_DIM + d)) * SEQ + s0 + sh;
    #pragma unroll
    for (int j = 0; j < 32; j += 2) {
        ushort2 u;
        u.x = f2bf(T[sh + j][d]);
        u.y = f2bf(T[sh + j + 1][d]);
        *(ushort2*)(op + j) = u;
    }
}

// ---------------- MFMA flash attention, 4-wave QBLK=64 ----------------------
// 1-D grid of 1024 blocks, bijectively remapped so XCD (bid&7) hosts 4 (b,h)
// groups entirely -> per-XCD K/V working set ~5 MB (L2-fit).  K (32 x 192)
// double-buffered in LDS; V read DIRECTLY from L2-hot Vmat (no LDS staging)
// -> LDS 29 KB -> 5 blocks/CU -> whole grid co-resident (no dispatch tail).
__global__ __launch_bounds__(256, 4) void flash_mfma_kernel(
    const unsigned short* __restrict__ qb16,     // (4096, 3072) roped bf16
    const unsigned short* __restrict__ kv_exp_b, // (4096, 4096) bf16
    const unsigned short* __restrict__ k_rope_b, // (4096, 64) bf16 roped
    const unsigned short* __restrict__ Vmat,     // [b][h][128][2048] bf16
    unsigned short* __restrict__ attnb)          // (4096, 2048) bf16
{
    const int bid  = blockIdx.x;
    const int xcd  = bid & 7, slot = bid >> 3;   // XCD-clustered remap
    const int grp  = xcd + 8 * (slot >> 5);      // (b,h) group 0..31
    const int qb   = 31 - (slot & 31);           // longest blocks first
    const int h    = grp & 15, b = grp >> 4;
    const int tid  = threadIdx.x;
    const int w    = tid >> 6;
    const int lane = tid & 63;
    const int n16  = lane & 15;
    const int quad = lane >> 4;

    const int q0 = qb * 64 + w * 16;             // this wave's 16 q rows
    const char* kNopeB = (const char*)(kv_exp_b + (size_t)b * SEQ * 4096 + h * 256);
    const char* kRopeB = (const char*)(k_rope_b + (size_t)b * SEQ * 64);
    const unsigned short* vBase = Vmat + (size_t)(b*NH + h) * V_DIM * SEQ;

    __shared__ unsigned short Ks[2][6144];       // 2 x 12 KB: 32 keys x 192
    __shared__ unsigned short Plds[4][16][40];   // 5 KB

    // ---- per-thread K staging source pointers ----
    // K-nope: 8192 B / tile = 2 rounds of 256 thr x 16 B
    const char* gK[2]; int lK[2];
    #pragma unroll
    for (int t = 0; t < 2; t++) {
        int idx = t * 256 + tid;                 // 0..511
        int kc = idx >> 7, key = (idx >> 2) & 31, sc = idx & 3;
        int scs = sc ^ ((key >> 1) & 3);         // pre-swizzled source
        gK[t] = kNopeB + (size_t)key * 8192 + kc * 64 + scs * 16;
        lK[t] = idx * 16;
    }
    // K-rope: 4096 B / tile = 1 round (kchunks 4,5)
    const char* gR; int lR;
    {
        int kc = tid >> 7, key = (tid >> 2) & 31, sc = tid & 3;
        int scs = sc ^ ((key >> 1) & 3);
        gR = kRopeB + (size_t)key * 128 + kc * 64 + scs * 16;
        lR = (512 + tid) * 16;
    }

    auto stage = [&](int kt, int bufsel) {
        const size_t koff = (size_t)kt * 32;
        #pragma unroll
        for (int t = 0; t < 2; t++)
            gl_lds16(gK[t] + koff * 8192, (char*)Ks[bufsel] + lK[t]);
        gl_lds16(gR + koff * 128, (char*)Ks[bufsel] + lR);
    };

    // ---- Q fragments straight from roped projection output ----
    short8 qf[6];
    {
        const unsigned short* qp = qb16 + ((size_t)(b*SEQ) + q0 + n16) * (NH*HD)
                                 + h * HD + quad * 8;
        #pragma unroll
        for (int kc = 0; kc < 6; kc++)
            qf[kc] = *(const short8*)(qp + kc * 32);
    }

    f32x4 O[8];
    #pragma unroll
    for (int c = 0; c < 8; c++) O[c] = (f32x4){0.f, 0.f, 0.f, 0.f};
    float mrow[4] = {-INFINITY, -INFINITY, -INFINITY, -INFINITY};
    float lrow[4] = {0.f, 0.f, 0.f, 0.f};

    const float scale = 0.07216878364870322f;    // 1/sqrt(192)
    const int swz = (quad ^ ((n16 >> 1) & 3)) * 8;
    const int ntB = 2 * qb + 2;                  // 32-key tiles for this block

    stage(0, 0);
    int cur = 0;
    for (int kt = 0; kt < ntB; kt++) {
        __syncthreads();                          // drains stage of buf `cur`
        if (kt + 1 < ntB) stage(kt + 1, cur ^ 1); // prefetch overlaps compute
        const int k0 = kt * 32;

        if (k0 <= q0 + 15) {                      // wave-uniform causal guard
            const unsigned short* KsB = Ks[cur];

            // ---- V fragments direct from L2-hot Vmat (issued early) ----
            short8 vfr[8];
            {
                const unsigned short* vp = vBase + k0 + quad * 8;
                #pragma unroll
                for (int c = 0; c < 8; c++)
                    vfr[c] = *(const short8*)(vp + (size_t)(c*16 + n16) * SEQ);
            }

            // ---- QK^T: two 16-key halves, 6 K-chunks each ----
            f32x4 S[2];
            __builtin_amdgcn_s_setprio(1);
            #pragma unroll
            for (int half = 0; half < 2; half++) {
                f32x4 acc = (f32x4){0.f, 0.f, 0.f, 0.f};
                const int keyoff = (half * 16 + n16) * 32 + swz;
                #pragma unroll
                for (int kc = 0; kc < 6; kc++) {
                    short8 kf = *(const short8*)(KsB + kc * 1024 + keyoff);
                    acc = __builtin_amdgcn_mfma_f32_16x16x32_bf16(qf[kc], kf, acc, 0, 0, 0);
                }
                S[half] = acc;
            }
            __builtin_amdgcn_s_setprio(0);

            // ---- online softmax in C-layout (row=quad*4+r, col=n16) ----
            float p0[4], p1[4], mnew[4];
            #pragma unroll
            for (int r = 0; r < 4; r++) {
                int row = q0 + quad*4 + r;
                float s0v = (k0 + n16      <= row) ? S[0][r] * scale : -INFINITY;
                float s1v = (k0 + 16 + n16 <= row) ? S[1][r] * scale : -INFINITY;
                p0[r] = s0v; p1[r] = s1v;
                float t = fmaxf(s0v, s1v);
                t = fmaxf(t, __shfl_xor(t, 1));
                t = fmaxf(t, __shfl_xor(t, 2));
                t = fmaxf(t, __shfl_xor(t, 4));
                t = fmaxf(t, __shfl_xor(t, 8));
                mnew[r] = fmaxf(mrow[r], t);
            }
            #pragma unroll
            for (int r = 0; r < 4; r++) {
                float alpha = __expf(mrow[r] - mnew[r]);
                float e0 = __expf(p0[r] - mnew[r]);
                float e1 = __expf(p1[r] - mnew[r]);
                float ps = e0 + e1;
                ps += __shfl_xor(ps, 1);
                ps += __shfl_xor(ps, 2);
                ps += __shfl_xor(ps, 4);
                ps += __shfl_xor(ps, 8);
                lrow[r] = lrow[r] * alpha + ps;
                mrow[r] = mnew[r];
                #pragma unroll
                for (int c = 0; c < 8; c++) O[c][r] *= alpha;
                unsigned short* pw = &Plds[w][quad*4 + r][0];
                pw[n16]      = f2bf(e0);
                pw[16 + n16] = f2bf(e1);
            }

            // ---- P as A-frag (per-wave LDS roundtrip), then PV ----
            short8 pf = *(const short8*)(&Plds[w][n16][quad * 8]);
            __builtin_amdgcn_s_setprio(1);
            #pragma unroll
            for (int c = 0; c < 8; c++)
                O[c] = __builtin_amdgcn_mfma_f32_16x16x32_bf16(pf, vfr[c], O[c], 0, 0, 0);
            __builtin_amdgcn_s_setprio(0);
        }
        cur ^= 1;
    }

    float invl[4];
    #pragma unroll
    for (int r = 0; r < 4; r++) invl[r] = 1.0f / lrow[r];
    #pragma unroll
    for (int c = 0; c < 8; c++) {
        #pragma unroll
        for (int r = 0; r < 4; r++) {
            size_t tok = (size_t)b * SEQ + q0 + quad*4 + r;
            attnb[tok * (NH*V_DIM) + h * V_DIM + c*16 + n16] = f2bf(O[c][r] * invl[r]);
        }
    }
}

// ---------------- launch ----------------
extern "C" void kernel_launch(void* const* d_in, const int* in_sizes, int n_in,
                              void* d_out, int out_size, void* d_ws, size_t ws_size,
                              hipStream_t stream)
{
    const float* x         = (const float*)d_in[0];
    const float* w_q_down  = (const float*)d_in[1];
    const float* w_q_up    = (const float*)d_in[2];
    const float* w_kv_down = (const float*)d_in[3];
    const float* kv_norm_w = (const float*)d_in[4];
    const float* w_kv_up   = (const float*)d_in[5];
    const float* w_out     = (const float*)d_in[6];
    float* out = (float*)d_out;
    float* ws  = (float*)d_ws;

    // ---- workspace layout (float offsets), total 41,746,432 floats (~167 MB) ----
    float*          table    = ws;                                // 131072
    unsigned short* xb       = (unsigned short*)(ws + 131072);    // 4096x2048 bf16
    unsigned short* qdb      = (unsigned short*)(ws + 4325376);   // 4096x1536 bf16
    unsigned short* qb16     = (unsigned short*)(ws + 7471104);   // 4096x3072 bf16
    float*          kv_full  = ws + 13762560;                     // 4096x576 fp32
    unsigned short* kv_cb    = (unsigned short*)(ws + 16121856);  // 4096x512 bf16
    unsigned short* k_rope_b = (unsigned short*)(ws + 17170432);  // 4096x64 bf16
    unsigned short* kv_exp_b = (unsigned short*)(ws + 17301504);  // 4096x4096 bf16
    unsigned short* Vmat     = (unsigned short*)(ws + 25690112);  // 2x16x128x2048 bf16
    unsigned short* attnb    = (unsigned short*)(ws + 29884416);  // 4096x2048 bf16
    unsigned short* wt1      = (unsigned short*)(ws + 34078720);  // 1536x2048
    unsigned short* wt2      = (unsigned short*)(ws + 35651584);  // 3072x1536
    unsigned short* wt3      = (unsigned short*)(ws + 38010880);  // 576x2048
    unsigned short* wt4      = (unsigned short*)(ws + 38600704);  // 4096x512
    unsigned short* wt5      = (unsigned short*)(ws + 39649280);  // 2048x2048 -> end 41746432

    rope_table_kernel<<<512, 256, 0, stream>>>(table);

    convert_bf16_kernel<<<ROWS*HID/1024, 256, 0, stream>>>(x, xb);
    transpose_bf16_kernel<<<dim3(1536/64, 2048/64), 256, 0, stream>>>(w_q_down, wt1, 2048, 1536);
    transpose_bf16_kernel<<<dim3(3072/64, 1536/64), 256, 0, stream>>>(w_q_up,   wt2, 1536, 3072);
    transpose_bf16_kernel<<<dim3(576/64,  2048/64), 256, 0, stream>>>(w_kv_down,wt3, 2048, 576);
    transpose_bf16_kernel<<<dim3(4096/64,  512/64), 256, 0, stream>>>(w_kv_up,  wt4, 512, 4096);
    transpose_bf16_kernel<<<dim3(2048/64, 2048/64), 256, 0, stream>>>(w_out,    wt5, 2048, 2048);

    // q chain: x@W1 -> q_down; q_down@W2 -> q (bf16); rope in place
    bgemm_kernel<128, true><<<dim3(1536/128, ROWS/128), 256, 0, stream>>>(xb,  wt1, qdb,  ROWS, 1536, 2048);
    bgemm_kernel<128, true><<<dim3(3072/128, ROWS/128), 256, 0, stream>>>(qdb, wt2, qb16, ROWS, 3072, 1536);
    q_rope_b_kernel<<<8192, 256, 0, stream>>>(qb16, table);

    // kv chain
    bgemm_kernel<64, false><<<dim3(576/64, ROWS/128), 256, 0, stream>>>(xb, wt3, kv_full, ROWS, 576, 2048);
    kv_norm_rope_kernel<<<ROWS, 256, 0, stream>>>(kv_full, kv_norm_w, table, kv_cb, k_rope_b);
    bgemm_kernel<128, true><<<dim3(4096/128, ROWS/128), 256, 0, stream>>>(kv_cb, wt4, kv_exp_b, ROWS, 4096, 512);
    pack_vt_kernel<<<dim3(SEQ/64, NH, BATCH), 256, 0, stream>>>(kv_exp_b, Vmat);

    // attention: 4 waves/block, QBLK=64, V direct-from-L2, XCD-clustered grid
    flash_mfma_kernel<<<dim3(1024), 256, 0, stream>>>(qb16, kv_exp_b, k_rope_b, Vmat, attnb);

    // output projection
    bgemm_kernel<128, false><<<dim3(2048/128, ROWS/128), 256, 0, stream>>>(attnb, wt5, out, ROWS, 2048, 2048);
}

// Round 3
// 539.711 us; speedup vs baseline: 1.4830x; 1.4830x over previous
//
#include <hip/hip_runtime.h>
#include <hip/hip_bf16.h>
#include <math.h>

// ---------------- problem constants ----------------
#define HID    2048
#define NH     16
#define D_NOPE 128
#define D_ROPE 64
#define HD     192      // HEAD_DIM
#define V_DIM  128
#define KV_RANK 512
#define Q_RANK  1536
#define BATCH  2
#define SEQ    2048
#define ROWS   (BATCH*SEQ)   // 4096

typedef __attribute__((ext_vector_type(8))) short short8;
typedef __attribute__((ext_vector_type(4))) float f32x4;

__device__ __forceinline__ unsigned short f2bf(float x) {
    unsigned int u = __float_as_uint(x);
    unsigned int r = (u + 0x7fffu + ((u >> 16) & 1u)) >> 16;
    return (unsigned short)r;
}
__device__ __forceinline__ float bf2f(unsigned short u) {
    return __uint_as_float((unsigned int)u << 16);
}

typedef const __attribute__((address_space(1))) unsigned int gu32;
typedef __attribute__((address_space(3))) unsigned int lu32;
__device__ __forceinline__ void gl_lds16(const void* g, void* l) {
    __builtin_amdgcn_global_load_lds((gu32*)g, (lu32*)l, 16, 0, 0);
}

// ---------------- RoPE cos/sin table ----------------
__global__ void rope_table_kernel(float* __restrict__ table) {
    int idx = blockIdx.x * 256 + threadIdx.x;   // < 2048*64
    int pos = idx >> 6, u = idx & 63;
    int i = u & 31;
    float invf = expf((float)i * (-9.210340371976184f / 32.0f));
    float ang = (float)pos * invf;
    table[idx] = (u < 32) ? cosf(ang) : sinf(ang);
}

// ---------------- fp32 -> bf16 elementwise ----------------
__global__ __launch_bounds__(256) void convert_bf16_kernel(
    const float* __restrict__ src, unsigned short* __restrict__ dst)
{
    size_t i = (size_t)(blockIdx.x * 256 + threadIdx.x) * 4;
    float4 v = *(const float4*)(src + i);
    ushort4 u;
    u.x = f2bf(v.x); u.y = f2bf(v.y); u.z = f2bf(v.z); u.w = f2bf(v.w);
    *(ushort4*)(dst + i) = u;
}

// ---------------- fp32 (K x N) -> bf16 transposed (N x K) ----------------
__global__ __launch_bounds__(256) void transpose_bf16_kernel(
    const float* __restrict__ src, unsigned short* __restrict__ dst, int K, int N)
{
    __shared__ float T[64][65];
    const int n0 = blockIdx.x * 64, k0 = blockIdx.y * 64;
    const int t = threadIdx.x;
    const int c4 = t & 15, r = t >> 4;
    #pragma unroll
    for (int i = 0; i < 4; i++) {
        int row = r + i * 16;
        float4 v = *(const float4*)(src + (size_t)(k0 + row) * N + n0 + c4 * 4);
        T[row][c4*4+0] = v.x; T[row][c4*4+1] = v.y;
        T[row][c4*4+2] = v.z; T[row][c4*4+3] = v.w;
    }
    __syncthreads();
    #pragma unroll
    for (int i = 0; i < 4; i++) {
        int nrow = r + i * 16;
        ushort4 u;
        u.x = f2bf(T[c4*4+0][nrow]); u.y = f2bf(T[c4*4+1][nrow]);
        u.z = f2bf(T[c4*4+2][nrow]); u.w = f2bf(T[c4*4+3][nrow]);
        *(ushort4*)(dst + (size_t)(n0 + nrow) * K + k0 + c4 * 4) = u;
    }
}

// ---------------- bf16 MFMA GEMM: C(M,N) = A(M,K) @ Bt(N,K)^T ----------------
template<int BN, bool OUT_BF16>
__global__ __launch_bounds__(256) void bgemm_kernel(
    const unsigned short* __restrict__ A,    // M x K bf16
    const unsigned short* __restrict__ Bt,   // N x K bf16
    void* __restrict__ Cv,                   // M x N (fp32 or bf16)
    int M, int N, int K)
{
    constexpr int NT = BN / 32;
    constexpr int NSLAB = 8 + BN / 16;
    const int tid  = threadIdx.x;
    const int w    = tid >> 6;
    const int lane = tid & 63;
    const int n16  = lane & 15, quad = lane >> 4;
    const int m0 = blockIdx.y * 128;
    const int n0 = blockIdx.x * BN;
    const int moff = (w & 1) * 64;
    const int noff = (w >> 1) * (NT * 16);

    __shared__ unsigned short As[128 * 32];
    __shared__ unsigned short Bs[BN * 32];

    const unsigned short* gp[4];
    unsigned short* lp[4];
    int ns = 0;
    const int rl = lane >> 2, sc = lane & 3;
    for (int s = w; s < NSLAB; s += 4) {
        int kc = sc ^ (((s * 16 + rl) >> 1) & 3);   // XOR swizzle
        if (s < 8) {
            gp[ns] = A + (size_t)(m0 + s * 16 + rl) * K + kc * 8;
            lp[ns] = As + s * 512;
        } else {
            int sb = s - 8;
            gp[ns] = Bt + (size_t)(n0 + sb * 16 + rl) * K + kc * 8;
            lp[ns] = Bs + sb * 512;
        }
        ns++;
    }

    const int swz = (quad ^ ((n16 >> 1) & 3)) * 8;
    int aoff[4], boff[NT];
    #pragma unroll
    for (int mt = 0; mt < 4; mt++) aoff[mt] = (moff + mt * 16 + n16) * 32 + swz;
    #pragma unroll
    for (int nt = 0; nt < NT; nt++) boff[nt] = (noff + nt * 16 + n16) * 32 + swz;

    f32x4 acc[4][NT];
    #pragma unroll
    for (int mt = 0; mt < 4; mt++)
        #pragma unroll
        for (int nt = 0; nt < NT; nt++) acc[mt][nt] = (f32x4){0.f, 0.f, 0.f, 0.f};

    for (int k0 = 0; k0 < K; k0 += 32) {
        #pragma unroll
        for (int j = 0; j < 4; j++) if (j < ns) gl_lds16(gp[j], lp[j]);
        #pragma unroll
        for (int j = 0; j < 4; j++) if (j < ns) gp[j] += 32;
        __syncthreads();

        short8 af[4], bfr[NT];
        #pragma unroll
        for (int mt = 0; mt < 4; mt++) af[mt] = *(const short8*)(As + aoff[mt]);
        #pragma unroll
        for (int nt = 0; nt < NT; nt++) bfr[nt] = *(const short8*)(Bs + boff[nt]);
        #pragma unroll
        for (int mt = 0; mt < 4; mt++)
            #pragma unroll
            for (int nt = 0; nt < NT; nt++)
                acc[mt][nt] = __builtin_amdgcn_mfma_f32_16x16x32_bf16(
                    af[mt], bfr[nt], acc[mt][nt], 0, 0, 0);
        __syncthreads();
    }

    #pragma unroll
    for (int mt = 0; mt < 4; mt++)
        #pragma unroll
        for (int nt = 0; nt < NT; nt++)
            #pragma unroll
            for (int r = 0; r < 4; r++) {
                size_t idx = (size_t)(m0 + moff + mt * 16 + quad * 4 + r) * N
                           + n0 + noff + nt * 16 + n16;
                if (OUT_BF16) ((unsigned short*)Cv)[idx] = f2bf(acc[mt][nt][r]);
                else          ((float*)Cv)[idx] = acc[mt][nt][r];
            }
}

// ---------------- RMSNorm(kv_c)->bf16 + RoPE(k_rope)->bf16 ----------------
__global__ __launch_bounds__(256) void kv_norm_rope_kernel(
    const float* __restrict__ kv_full,    // (4096, 576)
    const float* __restrict__ w,          // (512,)
    const float* __restrict__ table,
    unsigned short* __restrict__ kv_cb,   // (4096, 512) bf16
    unsigned short* __restrict__ k_rope_b)// (4096, 64) bf16 roped
{
    const int row = blockIdx.x;
    const int tid = threadIdx.x;
    const float* src = kv_full + (size_t)row * 576;
    float v0 = src[tid], v1 = src[tid + 256];
    float ss = v0*v0 + v1*v1;
    #pragma unroll
    for (int off = 32; off > 0; off >>= 1) ss += __shfl_down(ss, off);
    __shared__ float red[4];
    __shared__ float msh;
    if ((tid & 63) == 0) red[tid >> 6] = ss;
    __syncthreads();
    if (tid == 0) msh = (red[0] + red[1] + red[2] + red[3]) * (1.0f / 512.0f);
    __syncthreads();
    float f = rsqrtf(msh + 1e-6f);
    kv_cb[(size_t)row * 512 + tid]       = f2bf(v0 * f * w[tid]);
    kv_cb[(size_t)row * 512 + tid + 256] = f2bf(v1 * f * w[tid + 256]);
    if (tid < 32) {
        int pos = row & (SEQ - 1);
        float c = table[pos*64 + tid], s = table[pos*64 + 32 + tid];
        float x1 = src[512 + tid], x2 = src[512 + 32 + tid];
        k_rope_b[(size_t)row * 64 + tid]      = f2bf(x1*c - x2*s);
        k_rope_b[(size_t)row * 64 + 32 + tid] = f2bf(x2*c + x1*s);
    }
}

// ---------------- RoPE on q, in place, bf16 ----------------
__global__ __launch_bounds__(256) void q_rope_b_kernel(
    unsigned short* __restrict__ qb16, const float* __restrict__ table)
{
    int g = blockIdx.x * 8 + (threadIdx.x >> 5);  // (row,h) pair id, < 65536
    int i = threadIdx.x & 31;
    int row = g >> 4, h = g & 15;
    size_t base = (size_t)row * (NH*HD) + h * HD + D_NOPE;
    int pos = row & (SEQ - 1);
    float c = table[pos*64 + i], s = table[pos*64 + 32 + i];
    float x1 = bf2f(qb16[base + i]), x2 = bf2f(qb16[base + 32 + i]);
    qb16[base + i]      = f2bf(x1*c - x2*s);
    qb16[base + 32 + i] = f2bf(x2*c + x1*s);
}

// ---------------- pack V transposed: kv_exp_b(v) -> Vmat bf16 [b][h][128][s] --
__global__ __launch_bounds__(256) void pack_vt_kernel(
    const unsigned short* __restrict__ kv_exp_b, unsigned short* __restrict__ Vmat)
{
    const int st = blockIdx.x;     // 32 tiles of 64 tokens
    const int h  = blockIdx.y;
    const int b  = blockIdx.z;
    const int tid = threadIdx.x;
    const int s0 = st * 64;
    __shared__ float T[64][129];

    #pragma unroll
    for (int t = 0; t < 8; t++) {
        int idx = tid + t * 256;            // 0..2047 ushort4 slots
        int tokr = idx >> 5, c4 = idx & 31;
        ushort4 u = *(const ushort4*)(kv_exp_b +
            ((size_t)(b*SEQ) + s0 + tokr) * 4096 + h*256 + 128 + c4*4);
        T[tokr][c4*4+0] = bf2f(u.x); T[tokr][c4*4+1] = bf2f(u.y);
        T[tokr][c4*4+2] = bf2f(u.z); T[tokr][c4*4+3] = bf2f(u.w);
    }
    __syncthreads();

    int d = tid >> 1, sh = (tid & 1) * 32;
    unsigned short* op = Vmat + ((size_t)((b*NH + h) * V_DIM + d)) * SEQ + s0 + sh;
    #pragma unroll
    for (int j = 0; j < 32; j += 2) {
        ushort2 u;
        u.x = f2bf(T[sh + j][d]);
        u.y = f2bf(T[sh + j + 1][d]);
        *(ushort2*)(op + j) = u;
    }
}

// ---------------- MFMA flash attention, 4-wave QBLK=64, double-buffered ------
// 1-D grid of 1024 blocks, bijectively remapped so XCD (bid&7) hosts 4 (b,h)
// groups entirely -> per-XCD K/V working set ~L2-fit -> staging loads hit L2
// (~250 cy), which one-tile-ahead prefetch covers.  K (32x192) and V (128x32)
// both staged via global_load_lds, double-buffered, ONE barrier per tile, no
// mid-tile vmcnt waits (R2's V-direct drained the prefetch queue - reverted).
__global__ __launch_bounds__(256, 3) void flash_mfma_kernel(
    const unsigned short* __restrict__ qb16,     // (4096, 3072) roped bf16
    const unsigned short* __restrict__ kv_exp_b, // (4096, 4096) bf16
    const unsigned short* __restrict__ k_rope_b, // (4096, 64) bf16 roped
    const unsigned short* __restrict__ Vmat,     // [b][h][128][2048] bf16
    unsigned short* __restrict__ attnb)          // (4096, 2048) bf16
{
    const int bid  = blockIdx.x;
    const int xcd  = bid & 7, slot = bid >> 3;   // XCD-clustered remap
    const int grp  = xcd + 8 * (slot >> 5);      // (b,h) group 0..31
    const int qb   = 31 - (slot & 31);           // longest blocks first
    const int h    = grp & 15, b = grp >> 4;
    const int tid  = threadIdx.x;
    const int w    = tid >> 6;
    const int lane = tid & 63;
    const int n16  = lane & 15;
    const int quad = lane >> 4;

    const int q0 = qb * 64 + w * 16;             // this wave's 16 q rows
    const char* kNopeB = (const char*)(kv_exp_b + (size_t)b * SEQ * 4096 + h * 256);
    const char* kRopeB = (const char*)(k_rope_b + (size_t)b * SEQ * 64);
    const char* vByte  = (const char*)(Vmat + (size_t)(b*NH + h) * V_DIM * SEQ);

    __shared__ unsigned short Ks[2][6144];       // 2 x 12 KB: 32 keys x 192
    __shared__ unsigned short Vs[2][4096];       // 2 x 8 KB: 128 d x 32 keys
    __shared__ unsigned short Plds[4][16][40];   // 5 KB

    // ---- per-thread staging source pointers (advance by k0 per tile) ----
    // K-nope: 8192 B / tile = 2 rounds of 256 thr x 16 B
    const char* gK[2]; int lK[2];
    #pragma unroll
    for (int t = 0; t < 2; t++) {
        int idx = t * 256 + tid;                 // 0..511
        int kc = idx >> 7, key = (idx >> 2) & 31, sc = idx & 3;
        int scs = sc ^ ((key >> 1) & 3);         // pre-swizzled source
        gK[t] = kNopeB + (size_t)key * 8192 + kc * 64 + scs * 16;
        lK[t] = idx * 16;
    }
    // K-rope: 4096 B / tile = 1 round (kchunks 4,5)
    const char* gR; int lR;
    {
        int kc = tid >> 7, key = (tid >> 2) & 31, sc = tid & 3;
        int scs = sc ^ ((key >> 1) & 3);
        gR = kRopeB + (size_t)key * 128 + kc * 64 + scs * 16;
        lR = (512 + tid) * 16;
    }
    // V: 8192 B / tile = 2 rounds; row = d, 64 B = 32 keys
    const char* gV[2]; int lV[2];
    #pragma unroll
    for (int t = 0; t < 2; t++) {
        int idx = t * 256 + tid;
        int d = idx >> 2, sc = idx & 3;
        int scs = sc ^ ((d >> 1) & 3);
        gV[t] = vByte + (size_t)d * (SEQ * 2) + scs * 16;
        lV[t] = idx * 16;
    }

    auto stage = [&](int kt, int bufsel) {
        const size_t koff = (size_t)kt * 32;
        #pragma unroll
        for (int t = 0; t < 2; t++)
            gl_lds16(gK[t] + koff * 8192, (char*)Ks[bufsel] + lK[t]);
        gl_lds16(gR + koff * 128, (char*)Ks[bufsel] + lR);
        #pragma unroll
        for (int t = 0; t < 2; t++)
            gl_lds16(gV[t] + koff * 2, (char*)Vs[bufsel] + lV[t]);
    };

    // ---- Q fragments straight from roped projection output ----
    short8 qf[6];
    {
        const unsigned short* qp = qb16 + ((size_t)(b*SEQ) + q0 + n16) * (NH*HD)
                                 + h * HD + quad * 8;
        #pragma unroll
        for (int kc = 0; kc < 6; kc++)
            qf[kc] = *(const short8*)(qp + kc * 32);
    }

    f32x4 O[8];
    #pragma unroll
    for (int c = 0; c < 8; c++) O[c] = (f32x4){0.f, 0.f, 0.f, 0.f};
    float mrow[4] = {-INFINITY, -INFINITY, -INFINITY, -INFINITY};
    float lrow[4] = {0.f, 0.f, 0.f, 0.f};

    const float scale = 0.07216878364870322f;    // 1/sqrt(192)
    const int swz = (quad ^ ((n16 >> 1) & 3)) * 8;
    const int ntB = 2 * qb + 2;                  // 32-key tiles for this block

    stage(0, 0);
    int cur = 0;
    for (int kt = 0; kt < ntB; kt++) {
        __syncthreads();                          // drains stage of buf `cur`
        if (kt + 1 < ntB) stage(kt + 1, cur ^ 1); // prefetch overlaps compute
        const int k0 = kt * 32;

        if (k0 <= q0 + 15) {                      // wave-uniform causal guard
            const unsigned short* KsB = Ks[cur];
            const unsigned short* VsB = Vs[cur];

            // ---- QK^T: two 16-key halves, 6 K-chunks each ----
            f32x4 S[2];
            __builtin_amdgcn_s_setprio(1);
            #pragma unroll
            for (int half = 0; half < 2; half++) {
                f32x4 acc = (f32x4){0.f, 0.f, 0.f, 0.f};
                const int keyoff = (half * 16 + n16) * 32 + swz;
                #pragma unroll
                for (int kc = 0; kc < 6; kc++) {
                    short8 kf = *(const short8*)(KsB + kc * 1024 + keyoff);
                    acc = __builtin_amdgcn_mfma_f32_16x16x32_bf16(qf[kc], kf, acc, 0, 0, 0);
                }
                S[half] = acc;
            }
            __builtin_amdgcn_s_setprio(0);

            // ---- online softmax in C-layout (row=quad*4+r, col=n16) ----
            float p0[4], p1[4], mnew[4];
            #pragma unroll
            for (int r = 0; r < 4; r++) {
                int row = q0 + quad*4 + r;
                float s0v = (k0 + n16      <= row) ? S[0][r] * scale : -INFINITY;
                float s1v = (k0 + 16 + n16 <= row) ? S[1][r] * scale : -INFINITY;
                p0[r] = s0v; p1[r] = s1v;
                float t = fmaxf(s0v, s1v);
                t = fmaxf(t, __shfl_xor(t, 1));
                t = fmaxf(t, __shfl_xor(t, 2));
                t = fmaxf(t, __shfl_xor(t, 4));
                t = fmaxf(t, __shfl_xor(t, 8));
                mnew[r] = fmaxf(mrow[r], t);
            }
            #pragma unroll
            for (int r = 0; r < 4; r++) {
                float alpha = __expf(mrow[r] - mnew[r]);
                float e0 = __expf(p0[r] - mnew[r]);
                float e1 = __expf(p1[r] - mnew[r]);
                float ps = e0 + e1;
                ps += __shfl_xor(ps, 1);
                ps += __shfl_xor(ps, 2);
                ps += __shfl_xor(ps, 4);
                ps += __shfl_xor(ps, 8);
                lrow[r] = lrow[r] * alpha + ps;
                mrow[r] = mnew[r];
                #pragma unroll
                for (int c = 0; c < 8; c++) O[c][r] *= alpha;
                unsigned short* pw = &Plds[w][quad*4 + r][0];
                pw[n16]      = f2bf(e0);
                pw[16 + n16] = f2bf(e1);
            }

            // ---- P as A-frag (per-wave LDS roundtrip), then PV ----
            short8 pf = *(const short8*)(&Plds[w][n16][quad * 8]);
            __builtin_amdgcn_s_setprio(1);
            #pragma unroll
            for (int c = 0; c < 8; c++) {
                short8 vf = *(const short8*)(VsB + (c * 16 + n16) * 32 + swz);
                O[c] = __builtin_amdgcn_mfma_f32_16x16x32_bf16(pf, vf, O[c], 0, 0, 0);
            }
            __builtin_amdgcn_s_setprio(0);
        }
        cur ^= 1;
    }

    float invl[4];
    #pragma unroll
    for (int r = 0; r < 4; r++) invl[r] = 1.0f / lrow[r];
    #pragma unroll
    for (int c = 0; c < 8; c++) {
        #pragma unroll
        for (int r = 0; r < 4; r++) {
            size_t tok = (size_t)b * SEQ + q0 + quad*4 + r;
            attnb[tok * (NH*V_DIM) + h * V_DIM + c*16 + n16] = f2bf(O[c][r] * invl[r]);
        }
    }
}

// ---------------- launch ----------------
extern "C" void kernel_launch(void* const* d_in, const int* in_sizes, int n_in,
                              void* d_out, int out_size, void* d_ws, size_t ws_size,
                              hipStream_t stream)
{
    const float* x         = (const float*)d_in[0];
    const float* w_q_down  = (const float*)d_in[1];
    const float* w_q_up    = (const float*)d_in[2];
    const float* w_kv_down = (const float*)d_in[3];
    const float* kv_norm_w = (const float*)d_in[4];
    const float* w_kv_up   = (const float*)d_in[5];
    const float* w_out     = (const float*)d_in[6];
    float* out = (float*)d_out;
    float* ws  = (float*)d_ws;

    // ---- workspace layout (float offsets), total 41,746,432 floats (~167 MB) ----
    float*          table    = ws;                                // 131072
    unsigned short* xb       = (unsigned short*)(ws + 131072);    // 4096x2048 bf16
    unsigned short* qdb      = (unsigned short*)(ws + 4325376);   // 4096x1536 bf16
    unsigned short* qb16     = (unsigned short*)(ws + 7471104);   // 4096x3072 bf16
    float*          kv_full  = ws + 13762560;                     // 4096x576 fp32
    unsigned short* kv_cb    = (unsigned short*)(ws + 16121856);  // 4096x512 bf16
    unsigned short* k_rope_b = (unsigned short*)(ws + 17170432);  // 4096x64 bf16
    unsigned short* kv_exp_b = (unsigned short*)(ws + 17301504);  // 4096x4096 bf16
    unsigned short* Vmat     = (unsigned short*)(ws + 25690112);  // 2x16x128x2048 bf16
    unsigned short* attnb    = (unsigned short*)(ws + 29884416);  // 4096x2048 bf16
    unsigned short* wt1      = (unsigned short*)(ws + 34078720);  // 1536x2048
    unsigned short* wt2      = (unsigned short*)(ws + 35651584);  // 3072x1536
    unsigned short* wt3      = (unsigned short*)(ws + 38010880);  // 576x2048
    unsigned short* wt4      = (unsigned short*)(ws + 38600704);  // 4096x512
    unsigned short* wt5      = (unsigned short*)(ws + 39649280);  // 2048x2048 -> end 41746432

    rope_table_kernel<<<512, 256, 0, stream>>>(table);

    convert_bf16_kernel<<<ROWS*HID/1024, 256, 0, stream>>>(x, xb);
    transpose_bf16_kernel<<<dim3(1536/64, 2048/64), 256, 0, stream>>>(w_q_down, wt1, 2048, 1536);
    transpose_bf16_kernel<<<dim3(3072/64, 1536/64), 256, 0, stream>>>(w_q_up,   wt2, 1536, 3072);
    transpose_bf16_kernel<<<dim3(576/64,  2048/64), 256, 0, stream>>>(w_kv_down,wt3, 2048, 576);
    transpose_bf16_kernel<<<dim3(4096/64,  512/64), 256, 0, stream>>>(w_kv_up,  wt4, 512, 4096);
    transpose_bf16_kernel<<<dim3(2048/64, 2048/64), 256, 0, stream>>>(w_out,    wt5, 2048, 2048);

    // q chain: x@W1 -> q_down; q_down@W2 -> q (bf16); rope in place
    bgemm_kernel<128, true><<<dim3(1536/128, ROWS/128), 256, 0, stream>>>(xb,  wt1, qdb,  ROWS, 1536, 2048);
    bgemm_kernel<128, true><<<dim3(3072/128, ROWS/128), 256, 0, stream>>>(qdb, wt2, qb16, ROWS, 3072, 1536);
    q_rope_b_kernel<<<8192, 256, 0, stream>>>(qb16, table);

    // kv chain
    bgemm_kernel<64, false><<<dim3(576/64, ROWS/128), 256, 0, stream>>>(xb, wt3, kv_full, ROWS, 576, 2048);
    kv_norm_rope_kernel<<<ROWS, 256, 0, stream>>>(kv_full, kv_norm_w, table, kv_cb, k_rope_b);
    bgemm_kernel<128, true><<<dim3(4096/128, ROWS/128), 256, 0, stream>>>(kv_cb, wt4, kv_exp_b, ROWS, 4096, 512);
    pack_vt_kernel<<<dim3(SEQ/64, NH, BATCH), 256, 0, stream>>>(kv_exp_b, Vmat);

    // attention: R1 staging structure + XCD-clustered 1-D grid remap
    flash_mfma_kernel<<<dim3(1024), 256, 0, stream>>>(qb16, kv_exp_b, k_rope_b, Vmat, attnb);

    // output projection
    bgemm_kernel<128, false><<<dim3(2048/128, ROWS/128), 256, 0, stream>>>(attnb, wt5, out, ROWS, 2048, 2048);
}

// Round 4
// 489.659 us; speedup vs baseline: 1.6346x; 1.1022x over previous
//
#include <hip/hip_runtime.h>
#include <hip/hip_bf16.h>
#include <math.h>

// ---------------- problem constants ----------------
#define HID    2048
#define NH     16
#define D_NOPE 128
#define D_ROPE 64
#define HD     192      // HEAD_DIM
#define V_DIM  128
#define KV_RANK 512
#define Q_RANK  1536
#define BATCH  2
#define SEQ    2048
#define ROWS   (BATCH*SEQ)   // 4096

typedef __attribute__((ext_vector_type(8))) short short8;
typedef __attribute__((ext_vector_type(4))) float f32x4;

__device__ __forceinline__ unsigned short f2bf(float x) {
    unsigned int u = __float_as_uint(x);
    unsigned int r = (u + 0x7fffu + ((u >> 16) & 1u)) >> 16;
    return (unsigned short)r;
}
__device__ __forceinline__ float bf2f(unsigned short u) {
    return __uint_as_float((unsigned int)u << 16);
}

typedef const __attribute__((address_space(1))) unsigned int gu32;
typedef __attribute__((address_space(3))) unsigned int lu32;
__device__ __forceinline__ void gl_lds16(const void* g, void* l) {
    __builtin_amdgcn_global_load_lds((gu32*)g, (lu32*)l, 16, 0, 0);
}

// DPP lane permute within a 16-lane row (VALU pipe, no LDS traffic)
template<int CTRL>
__device__ __forceinline__ float dpp_mv(float x) {
    return __int_as_float(__builtin_amdgcn_update_dpp(
        __float_as_int(x), __float_as_int(x), CTRL, 0xF, 0xF, true));
}
// max over the 16 contiguous lanes of a DPP row
__device__ __forceinline__ float rowmax16(float x) {
    x = fmaxf(x, dpp_mv<0xB1>(x));   // quad_perm [1,0,3,2]  (xor 1)
    x = fmaxf(x, dpp_mv<0x4E>(x));   // quad_perm [2,3,0,1]  (xor 2)
    x = fmaxf(x, dpp_mv<0x141>(x));  // row_half_mirror      (combine quads)
    x = fmaxf(x, dpp_mv<0x140>(x));  // row_mirror           (combine halves)
    return x;
}

// ---------------- RoPE cos/sin table ----------------
__global__ void rope_table_kernel(float* __restrict__ table) {
    int idx = blockIdx.x * 256 + threadIdx.x;   // < 2048*64
    int pos = idx >> 6, u = idx & 63;
    int i = u & 31;
    float invf = expf((float)i * (-9.210340371976184f / 32.0f));
    float ang = (float)pos * invf;
    table[idx] = (u < 32) ? cosf(ang) : sinf(ang);
}

// ---------------- fp32 -> bf16 elementwise ----------------
__global__ __launch_bounds__(256) void convert_bf16_kernel(
    const float* __restrict__ src, unsigned short* __restrict__ dst)
{
    size_t i = (size_t)(blockIdx.x * 256 + threadIdx.x) * 4;
    float4 v = *(const float4*)(src + i);
    ushort4 u;
    u.x = f2bf(v.x); u.y = f2bf(v.y); u.z = f2bf(v.z); u.w = f2bf(v.w);
    *(ushort4*)(dst + i) = u;
}

// ---------------- fp32 (K x N) -> bf16 transposed (N x K) ----------------
__global__ __launch_bounds__(256) void transpose_bf16_kernel(
    const float* __restrict__ src, unsigned short* __restrict__ dst, int K, int N)
{
    __shared__ float T[64][65];
    const int n0 = blockIdx.x * 64, k0 = blockIdx.y * 64;
    const int t = threadIdx.x;
    const int c4 = t & 15, r = t >> 4;
    #pragma unroll
    for (int i = 0; i < 4; i++) {
        int row = r + i * 16;
        float4 v = *(const float4*)(src + (size_t)(k0 + row) * N + n0 + c4 * 4);
        T[row][c4*4+0] = v.x; T[row][c4*4+1] = v.y;
        T[row][c4*4+2] = v.z; T[row][c4*4+3] = v.w;
    }
    __syncthreads();
    #pragma unroll
    for (int i = 0; i < 4; i++) {
        int nrow = r + i * 16;
        ushort4 u;
        u.x = f2bf(T[c4*4+0][nrow]); u.y = f2bf(T[c4*4+1][nrow]);
        u.z = f2bf(T[c4*4+2][nrow]); u.w = f2bf(T[c4*4+3][nrow]);
        *(ushort4*)(dst + (size_t)(n0 + nrow) * K + k0 + c4 * 4) = u;
    }
}

// ---------------- bf16 MFMA GEMM: C(M,N) = A(M,K) @ Bt(N,K)^T ----------------
template<int BN, bool OUT_BF16>
__global__ __launch_bounds__(256) void bgemm_kernel(
    const unsigned short* __restrict__ A,    // M x K bf16
    const unsigned short* __restrict__ Bt,   // N x K bf16
    void* __restrict__ Cv,                   // M x N (fp32 or bf16)
    int M, int N, int K)
{
    constexpr int NT = BN / 32;
    constexpr int NSLAB = 8 + BN / 16;
    const int tid  = threadIdx.x;
    const int w    = tid >> 6;
    const int lane = tid & 63;
    const int n16  = lane & 15, quad = lane >> 4;
    const int m0 = blockIdx.y * 128;
    const int n0 = blockIdx.x * BN;
    const int moff = (w & 1) * 64;
    const int noff = (w >> 1) * (NT * 16);

    __shared__ unsigned short As[128 * 32];
    __shared__ unsigned short Bs[BN * 32];

    const unsigned short* gp[4];
    unsigned short* lp[4];
    int ns = 0;
    const int rl = lane >> 2, sc = lane & 3;
    for (int s = w; s < NSLAB; s += 4) {
        int kc = sc ^ (((s * 16 + rl) >> 1) & 3);   // XOR swizzle
        if (s < 8) {
            gp[ns] = A + (size_t)(m0 + s * 16 + rl) * K + kc * 8;
            lp[ns] = As + s * 512;
        } else {
            int sb = s - 8;
            gp[ns] = Bt + (size_t)(n0 + sb * 16 + rl) * K + kc * 8;
            lp[ns] = Bs + sb * 512;
        }
        ns++;
    }

    const int swz = (quad ^ ((n16 >> 1) & 3)) * 8;
    int aoff[4], boff[NT];
    #pragma unroll
    for (int mt = 0; mt < 4; mt++) aoff[mt] = (moff + mt * 16 + n16) * 32 + swz;
    #pragma unroll
    for (int nt = 0; nt < NT; nt++) boff[nt] = (noff + nt * 16 + n16) * 32 + swz;

    f32x4 acc[4][NT];
    #pragma unroll
    for (int mt = 0; mt < 4; mt++)
        #pragma unroll
        for (int nt = 0; nt < NT; nt++) acc[mt][nt] = (f32x4){0.f, 0.f, 0.f, 0.f};

    for (int k0 = 0; k0 < K; k0 += 32) {
        #pragma unroll
        for (int j = 0; j < 4; j++) if (j < ns) gl_lds16(gp[j], lp[j]);
        #pragma unroll
        for (int j = 0; j < 4; j++) if (j < ns) gp[j] += 32;
        __syncthreads();

        short8 af[4], bfr[NT];
        #pragma unroll
        for (int mt = 0; mt < 4; mt++) af[mt] = *(const short8*)(As + aoff[mt]);
        #pragma unroll
        for (int nt = 0; nt < NT; nt++) bfr[nt] = *(const short8*)(Bs + boff[nt]);
        #pragma unroll
        for (int mt = 0; mt < 4; mt++)
            #pragma unroll
            for (int nt = 0; nt < NT; nt++)
                acc[mt][nt] = __builtin_amdgcn_mfma_f32_16x16x32_bf16(
                    af[mt], bfr[nt], acc[mt][nt], 0, 0, 0);
        __syncthreads();
    }

    #pragma unroll
    for (int mt = 0; mt < 4; mt++)
        #pragma unroll
        for (int nt = 0; nt < NT; nt++)
            #pragma unroll
            for (int r = 0; r < 4; r++) {
                size_t idx = (size_t)(m0 + moff + mt * 16 + quad * 4 + r) * N
                           + n0 + noff + nt * 16 + n16;
                if (OUT_BF16) ((unsigned short*)Cv)[idx] = f2bf(acc[mt][nt][r]);
                else          ((float*)Cv)[idx] = acc[mt][nt][r];
            }
}

// ---------------- RMSNorm(kv_c)->bf16 + RoPE(k_rope)->bf16 ----------------
__global__ __launch_bounds__(256) void kv_norm_rope_kernel(
    const float* __restrict__ kv_full,    // (4096, 576)
    const float* __restrict__ w,          // (512,)
    const float* __restrict__ table,
    unsigned short* __restrict__ kv_cb,   // (4096, 512) bf16
    unsigned short* __restrict__ k_rope_b)// (4096, 64) bf16 roped
{
    const int row = blockIdx.x;
    const int tid = threadIdx.x;
    const float* src = kv_full + (size_t)row * 576;
    float v0 = src[tid], v1 = src[tid + 256];
    float ss = v0*v0 + v1*v1;
    #pragma unroll
    for (int off = 32; off > 0; off >>= 1) ss += __shfl_down(ss, off);
    __shared__ float red[4];
    __shared__ float msh;
    if ((tid & 63) == 0) red[tid >> 6] = ss;
    __syncthreads();
    if (tid == 0) msh = (red[0] + red[1] + red[2] + red[3]) * (1.0f / 512.0f);
    __syncthreads();
    float f = rsqrtf(msh + 1e-6f);
    kv_cb[(size_t)row * 512 + tid]       = f2bf(v0 * f * w[tid]);
    kv_cb[(size_t)row * 512 + tid + 256] = f2bf(v1 * f * w[tid + 256]);
    if (tid < 32) {
        int pos = row & (SEQ - 1);
        float c = table[pos*64 + tid], s = table[pos*64 + 32 + tid];
        float x1 = src[512 + tid], x2 = src[512 + 32 + tid];
        k_rope_b[(size_t)row * 64 + tid]      = f2bf(x1*c - x2*s);
        k_rope_b[(size_t)row * 64 + 32 + tid] = f2bf(x2*c + x1*s);
    }
}

// ---------------- RoPE on q, in place, bf16 ----------------
__global__ __launch_bounds__(256) void q_rope_b_kernel(
    unsigned short* __restrict__ qb16, const float* __restrict__ table)
{
    int g = blockIdx.x * 8 + (threadIdx.x >> 5);  // (row,h) pair id, < 65536
    int i = threadIdx.x & 31;
    int row = g >> 4, h = g & 15;
    size_t base = (size_t)row * (NH*HD) + h * HD + D_NOPE;
    int pos = row & (SEQ - 1);
    float c = table[pos*64 + i], s = table[pos*64 + 32 + i];
    float x1 = bf2f(qb16[base + i]), x2 = bf2f(qb16[base + 32 + i]);
    qb16[base + i]      = f2bf(x1*c - x2*s);
    qb16[base + 32 + i] = f2bf(x2*c + x1*s);
}

// ---------------- pack V transposed: kv_exp_b(v) -> Vmat bf16 [b][h][128][s] --
__global__ __launch_bounds__(256) void pack_vt_kernel(
    const unsigned short* __restrict__ kv_exp_b, unsigned short* __restrict__ Vmat)
{
    const int st = blockIdx.x;     // 32 tiles of 64 tokens
    const int h  = blockIdx.y;
    const int b  = blockIdx.z;
    const int tid = threadIdx.x;
    const int s0 = st * 64;
    __shared__ float T[64][129];

    #pragma unroll
    for (int t = 0; t < 8; t++) {
        int idx = tid + t * 256;            // 0..2047 ushort4 slots
        int tokr = idx >> 5, c4 = idx & 31;
        ushort4 u = *(const ushort4*)(kv_exp_b +
            ((size_t)(b*SEQ) + s0 + tokr) * 4096 + h*256 + 128 + c4*4);
        T[tokr][c4*4+0] = bf2f(u.x); T[tokr][c4*4+1] = bf2f(u.y);
        T[tokr][c4*4+2] = bf2f(u.z); T[tokr][c4*4+3] = bf2f(u.w);
    }
    __syncthreads();

    int d = tid >> 1, sh = (tid & 1) * 32;
    unsigned short* op = Vmat + ((size_t)((b*NH + h) * V_DIM + d)) * SEQ + s0 + sh;
    #pragma unroll
    for (int j = 0; j < 32; j += 2) {
        ushort2 u;
        u.x = f2bf(T[sh + j][d]);
        u.y = f2bf(T[sh + j + 1][d]);
        *(ushort2*)(op + j) = u;
    }
}

// ---------------- MFMA flash attention, 4-wave QBLK=64, double-buffered ------
// R3 structure (XCD-clustered remap + dbuf staging, 1 barrier/tile) with the
// softmax LDS-pipe load cut: max-reduce via DPP (VALU pipe, was 16 ds ops),
// denominator l accumulated by a 9th ones-column PV MFMA (was 16 ds ops),
// defer-max (skip alpha/rescale when tile max growth <= 6).
__global__ __launch_bounds__(256, 3) void flash_mfma_kernel(
    const unsigned short* __restrict__ qb16,     // (4096, 3072) roped bf16
    const unsigned short* __restrict__ kv_exp_b, // (4096, 4096) bf16
    const unsigned short* __restrict__ k_rope_b, // (4096, 64) bf16 roped
    const unsigned short* __restrict__ Vmat,     // [b][h][128][2048] bf16
    unsigned short* __restrict__ attnb)          // (4096, 2048) bf16
{
    const int bid  = blockIdx.x;
    const int xcd  = bid & 7, slot = bid >> 3;   // XCD-clustered remap
    const int grp  = xcd + 8 * (slot >> 5);      // (b,h) group 0..31
    const int qb   = 31 - (slot & 31);           // longest blocks first
    const int h    = grp & 15, b = grp >> 4;
    const int tid  = threadIdx.x;
    const int w    = tid >> 6;
    const int lane = tid & 63;
    const int n16  = lane & 15;
    const int quad = lane >> 4;

    const int q0 = qb * 64 + w * 16;             // this wave's 16 q rows
    const char* kNopeB = (const char*)(kv_exp_b + (size_t)b * SEQ * 4096 + h * 256);
    const char* kRopeB = (const char*)(k_rope_b + (size_t)b * SEQ * 64);
    const char* vByte  = (const char*)(Vmat + (size_t)(b*NH + h) * V_DIM * SEQ);

    __shared__ unsigned short Ks[2][6144];       // 2 x 12 KB: 32 keys x 192
    __shared__ unsigned short Vs[2][4096];       // 2 x 8 KB: 128 d x 32 keys
    __shared__ unsigned short Plds[4][16][40];   // 5 KB

    // ---- per-thread staging source pointers (advance by k0 per tile) ----
    // K-nope: 8192 B / tile = 2 rounds of 256 thr x 16 B
    const char* gK[2]; int lK[2];
    #pragma unroll
    for (int t = 0; t < 2; t++) {
        int idx = t * 256 + tid;                 // 0..511
        int kc = idx >> 7, key = (idx >> 2) & 31, sc = idx & 3;
        int scs = sc ^ ((key >> 1) & 3);         // pre-swizzled source
        gK[t] = kNopeB + (size_t)key * 8192 + kc * 64 + scs * 16;
        lK[t] = idx * 16;
    }
    // K-rope: 4096 B / tile = 1 round (kchunks 4,5)
    const char* gR; int lR;
    {
        int kc = tid >> 7, key = (tid >> 2) & 31, sc = tid & 3;
        int scs = sc ^ ((key >> 1) & 3);
        gR = kRopeB + (size_t)key * 128 + kc * 64 + scs * 16;
        lR = (512 + tid) * 16;
    }
    // V: 8192 B / tile = 2 rounds; row = d, 64 B = 32 keys
    const char* gV[2]; int lV[2];
    #pragma unroll
    for (int t = 0; t < 2; t++) {
        int idx = t * 256 + tid;
        int d = idx >> 2, sc = idx & 3;
        int scs = sc ^ ((d >> 1) & 3);
        gV[t] = vByte + (size_t)d * (SEQ * 2) + scs * 16;
        lV[t] = idx * 16;
    }

    auto stage = [&](int kt, int bufsel) {
        const size_t koff = (size_t)kt * 32;
        #pragma unroll
        for (int t = 0; t < 2; t++)
            gl_lds16(gK[t] + koff * 8192, (char*)Ks[bufsel] + lK[t]);
        gl_lds16(gR + koff * 128, (char*)Ks[bufsel] + lR);
        #pragma unroll
        for (int t = 0; t < 2; t++)
            gl_lds16(gV[t] + koff * 2, (char*)Vs[bufsel] + lV[t]);
    };

    // ---- Q fragments straight from roped projection output ----
    short8 qf[6];
    {
        const unsigned short* qp = qb16 + ((size_t)(b*SEQ) + q0 + n16) * (NH*HD)
                                 + h * HD + quad * 8;
        #pragma unroll
        for (int kc = 0; kc < 6; kc++)
            qf[kc] = *(const short8*)(qp + kc * 32);
    }

    // ones B-frag for the denominator MFMA (bf16 1.0 in every slot)
    short8 onesf;
    #pragma unroll
    for (int j = 0; j < 8; j++) onesf[j] = (short)0x3F80;

    f32x4 O[9];                                  // O[0..7] = out, O[8] = l
    #pragma unroll
    for (int c = 0; c < 9; c++) O[c] = (f32x4){0.f, 0.f, 0.f, 0.f};
    float mrow[4] = {-INFINITY, -INFINITY, -INFINITY, -INFINITY};

    const float scale = 0.07216878364870322f;    // 1/sqrt(192)
    const int swz = (quad ^ ((n16 >> 1) & 3)) * 8;
    const int ntB = 2 * qb + 2;                  // 32-key tiles for this block

    stage(0, 0);
    int cur = 0;
    for (int kt = 0; kt < ntB; kt++) {
        __syncthreads();                          // drains stage of buf `cur`
        if (kt + 1 < ntB) stage(kt + 1, cur ^ 1); // prefetch overlaps compute
        const int k0 = kt * 32;

        if (k0 <= q0 + 15) {                      // wave-uniform causal guard
            const unsigned short* KsB = Ks[cur];
            const unsigned short* VsB = Vs[cur];

            // ---- QK^T: two 16-key halves, 6 K-chunks each ----
            f32x4 S[2];
            __builtin_amdgcn_s_setprio(1);
            #pragma unroll
            for (int half = 0; half < 2; half++) {
                f32x4 acc = (f32x4){0.f, 0.f, 0.f, 0.f};
                const int keyoff = (half * 16 + n16) * 32 + swz;
                #pragma unroll
                for (int kc = 0; kc < 6; kc++) {
                    short8 kf = *(const short8*)(KsB + kc * 1024 + keyoff);
                    acc = __builtin_amdgcn_mfma_f32_16x16x32_bf16(qf[kc], kf, acc, 0, 0, 0);
                }
                S[half] = acc;
            }
            __builtin_amdgcn_s_setprio(0);

            // ---- online softmax: DPP row-max + defer-max (THR=6) ----
            // causal geometry gives k0 <= q0 for all active tiles, so every
            // row has >=1 valid key -> tmax finite, no NaN paths.
            float p0[4], p1[4], tmax[4];
            float growth = -INFINITY;
            #pragma unroll
            for (int r = 0; r < 4; r++) {
                int row = q0 + quad*4 + r;
                float s0v = (k0 + n16      <= row) ? S[0][r] * scale : -INFINITY;
                float s1v = (k0 + 16 + n16 <= row) ? S[1][r] * scale : -INFINITY;
                p0[r] = s0v; p1[r] = s1v;
                tmax[r] = rowmax16(fmaxf(s0v, s1v));
                growth = fmaxf(growth, tmax[r] - mrow[r]);
            }
            if (!__all(growth <= 6.0f)) {         // rescale only on real growth
                #pragma unroll
                for (int r = 0; r < 4; r++) {
                    float mnew = fmaxf(mrow[r], tmax[r]);
                    float alpha = __expf(mrow[r] - mnew);
                    mrow[r] = mnew;
                    #pragma unroll
                    for (int c = 0; c < 9; c++) O[c][r] *= alpha;
                }
            }
            #pragma unroll
            for (int r = 0; r < 4; r++) {
                float e0 = __expf(p0[r] - mrow[r]);   // bounded by e^6
                float e1 = __expf(p1[r] - mrow[r]);
                unsigned short* pw = &Plds[w][quad*4 + r][0];
                pw[n16]      = f2bf(e0);
                pw[16 + n16] = f2bf(e1);
            }

            // ---- P as A-frag (per-wave LDS roundtrip), then PV (+l) ----
            short8 pf = *(const short8*)(&Plds[w][n16][quad * 8]);
            __builtin_amdgcn_s_setprio(1);
            #pragma unroll
            for (int c = 0; c < 8; c++) {
                short8 vf = *(const short8*)(VsB + (c * 16 + n16) * 32 + swz);
                O[c] = __builtin_amdgcn_mfma_f32_16x16x32_bf16(pf, vf, O[c], 0, 0, 0);
            }
            O[8] = __builtin_amdgcn_mfma_f32_16x16x32_bf16(pf, onesf, O[8], 0, 0, 0);
            __builtin_amdgcn_s_setprio(0);
        }
        cur ^= 1;
    }

    float invl[4];
    #pragma unroll
    for (int r = 0; r < 4; r++) invl[r] = 1.0f / O[8][r];
    #pragma unroll
    for (int c = 0; c < 8; c++) {
        #pragma unroll
        for (int r = 0; r < 4; r++) {
            size_t tok = (size_t)b * SEQ + q0 + quad*4 + r;
            attnb[tok * (NH*V_DIM) + h * V_DIM + c*16 + n16] = f2bf(O[c][r] * invl[r]);
        }
    }
}

// ---------------- launch ----------------
extern "C" void kernel_launch(void* const* d_in, const int* in_sizes, int n_in,
                              void* d_out, int out_size, void* d_ws, size_t ws_size,
                              hipStream_t stream)
{
    const float* x         = (const float*)d_in[0];
    const float* w_q_down  = (const float*)d_in[1];
    const float* w_q_up    = (const float*)d_in[2];
    const float* w_kv_down = (const float*)d_in[3];
    const float* kv_norm_w = (const float*)d_in[4];
    const float* w_kv_up   = (const float*)d_in[5];
    const float* w_out     = (const float*)d_in[6];
    float* out = (float*)d_out;
    float* ws  = (float*)d_ws;

    // ---- workspace layout (float offsets), total 41,746,432 floats (~167 MB) ----
    float*          table    = ws;                                // 131072
    unsigned short* xb       = (unsigned short*)(ws + 131072);    // 4096x2048 bf16
    unsigned short* qdb      = (unsigned short*)(ws + 4325376);   // 4096x1536 bf16
    unsigned short* qb16     = (unsigned short*)(ws + 7471104);   // 4096x3072 bf16
    float*          kv_full  = ws + 13762560;                     // 4096x576 fp32
    unsigned short* kv_cb    = (unsigned short*)(ws + 16121856);  // 4096x512 bf16
    unsigned short* k_rope_b = (unsigned short*)(ws + 17170432);  // 4096x64 bf16
    unsigned short* kv_exp_b = (unsigned short*)(ws + 17301504);  // 4096x4096 bf16
    unsigned short* Vmat     = (unsigned short*)(ws + 25690112);  // 2x16x128x2048 bf16
    unsigned short* attnb    = (unsigned short*)(ws + 29884416);  // 4096x2048 bf16
    unsigned short* wt1      = (unsigned short*)(ws + 34078720);  // 1536x2048
    unsigned short* wt2      = (unsigned short*)(ws + 35651584);  // 3072x1536
    unsigned short* wt3      = (unsigned short*)(ws + 38010880);  // 576x2048
    unsigned short* wt4      = (unsigned short*)(ws + 38600704);  // 4096x512
    unsigned short* wt5      = (unsigned short*)(ws + 39649280);  // 2048x2048 -> end 41746432

    rope_table_kernel<<<512, 256, 0, stream>>>(table);

    convert_bf16_kernel<<<ROWS*HID/1024, 256, 0, stream>>>(x, xb);
    transpose_bf16_kernel<<<dim3(1536/64, 2048/64), 256, 0, stream>>>(w_q_down, wt1, 2048, 1536);
    transpose_bf16_kernel<<<dim3(3072/64, 1536/64), 256, 0, stream>>>(w_q_up,   wt2, 1536, 3072);
    transpose_bf16_kernel<<<dim3(576/64,  2048/64), 256, 0, stream>>>(w_kv_down,wt3, 2048, 576);
    transpose_bf16_kernel<<<dim3(4096/64,  512/64), 256, 0, stream>>>(w_kv_up,  wt4, 512, 4096);
    transpose_bf16_kernel<<<dim3(2048/64, 2048/64), 256, 0, stream>>>(w_out,    wt5, 2048, 2048);

    // q chain: x@W1 -> q_down; q_down@W2 -> q (bf16); rope in place
    bgemm_kernel<128, true><<<dim3(1536/128, ROWS/128), 256, 0, stream>>>(xb,  wt1, qdb,  ROWS, 1536, 2048);
    bgemm_kernel<128, true><<<dim3(3072/128, ROWS/128), 256, 0, stream>>>(qdb, wt2, qb16, ROWS, 3072, 1536);
    q_rope_b_kernel<<<8192, 256, 0, stream>>>(qb16, table);

    // kv chain
    bgemm_kernel<64, false><<<dim3(576/64, ROWS/128), 256, 0, stream>>>(xb, wt3, kv_full, ROWS, 576, 2048);
    kv_norm_rope_kernel<<<ROWS, 256, 0, stream>>>(kv_full, kv_norm_w, table, kv_cb, k_rope_b);
    bgemm_kernel<128, true><<<dim3(4096/128, ROWS/128), 256, 0, stream>>>(kv_cb, wt4, kv_exp_b, ROWS, 4096, 512);
    pack_vt_kernel<<<dim3(SEQ/64, NH, BATCH), 256, 0, stream>>>(kv_exp_b, Vmat);

    // attention: R3 structure + DPP softmax + ones-MFMA denominator
    flash_mfma_kernel<<<dim3(1024), 256, 0, stream>>>(qb16, kv_exp_b, k_rope_b, Vmat, attnb);

    // output projection
    bgemm_kernel<128, false><<<dim3(2048/128, ROWS/128), 256, 0, stream>>>(attnb, wt5, out, ROWS, 2048, 2048);
}